// Round 7
// baseline (318.598 us; speedup 1.0000x reference)
//
#include <hip/hip_runtime.h>
#include <stdint.h>

#define B_ 64
#define C_ 4
#define R_ 64
#define E_ 512
#define P_ 4
#define OS_ 256
#define L_ 32768          // R_*E_
#define K_ 131072         // L_*P_
#define M_ 256            // B_*C_

#define BM 256
#define BN 128
#define BK 32
#define Z_ 256            // split-K slices; grid = 512 = 2 blocks/CU
#define KCH (K_/Z_)       // 512
#define ITERS (KCH/BK)    // 16

#define XSTR 513          // padded x-row stride (f32): bank=(bcl+e)%32

typedef float  floatx4 __attribute__((ext_vector_type(4)));
typedef short  shortx8 __attribute__((ext_vector_type(8)));

// async global->LDS, 16 B per lane; LDS dest is wave-uniform base + lane*16
#define GLDS16(g, l) __builtin_amdgcn_global_load_lds(                      \
    (const __attribute__((address_space(1))) void*)(g),                     \
    (__attribute__((address_space(3))) void*)(l), 16, 0, 0)

static __device__ __forceinline__ unsigned short f2bf(float f) {
  union { float f; unsigned int u; } v; v.f = f;
  unsigned int u = v.u;
  u += 0x7fffu + ((u >> 16) & 1u);   // RNE
  return (unsigned short)(u >> 16);
}

// ---------------------------------------------------------------------------
// convW_k v2: W[n][k] f32 -> W2[k8][n][8] bf16. Same verified layout/swizzle
// as R6; loads BATCHED: 16 dwordx4 in flight per wave (was 2 — load-use
// adjacency made R5/R6 run at 2.1 TB/s, latency-bound). nt=1's loads issue
// before nt=0's store phase so they fly across the barrier.
// ---------------------------------------------------------------------------
__global__ __launch_bounds__(512, 4) void convW_k(
    const float* __restrict__ W, unsigned short* __restrict__ W2) {
  __shared__ __align__(16) unsigned short T[64 * 64 * 8];   // 64 KB
  const int t    = threadIdx.x;
  const int lane = t & 63;
  const int wv   = t >> 6;
  const int kb   = blockIdx.x >> 1;     // 0..255 (512-k chunk)
  const int nh   = blockIdx.x & 1;      // n-half

  const float* wbase = W + (size_t)kb * 512 + lane * 8;
  float4 ra[8], rb[8];

  // batch-load tile nt=0 (16 independent dwordx4)
  #pragma unroll
  for (int j = 0; j < 8; ++j) {
    const float* wp = wbase + (size_t)(nh * 128 + j * 8 + wv) * K_;
    ra[j] = *(const float4*)(wp);
    rb[j] = *(const float4*)(wp + 4);
  }

  #pragma unroll 1
  for (int nt = 0; nt < 2; ++nt) {
    const int n0 = nh * 128 + nt * 64;
    // convert current tile into T (XOR-swizzled granules)
    #pragma unroll
    for (int j = 0; j < 8; ++j) {
      const int n = j * 8 + wv;         // tile-local
      shortx8 g;
      g[0] = (short)f2bf(ra[j].x); g[1] = (short)f2bf(ra[j].y);
      g[2] = (short)f2bf(ra[j].z); g[3] = (short)f2bf(ra[j].w);
      g[4] = (short)f2bf(rb[j].x); g[5] = (short)f2bf(rb[j].y);
      g[6] = (short)f2bf(rb[j].z); g[7] = (short)f2bf(rb[j].w);
      *(shortx8*)(&T[((size_t)lane * 64 + (n ^ lane)) * 8]) = g;   // k8loc=lane
    }
    // issue next tile's loads now — they stay in flight across barrier+stores
    if (nt == 0) {
      #pragma unroll
      for (int j = 0; j < 8; ++j) {
        const float* wp = wbase + (size_t)(nh * 128 + 64 + j * 8 + wv) * K_;
        ra[j] = *(const float4*)(wp);
        rb[j] = *(const float4*)(wp + 4);
      }
    }
    __syncthreads();
    // store: per instr a wave writes 1 KB contiguous (one k8 row-slice)
    #pragma unroll
    for (int i = 0; i < 8; ++i) {
      const int k8loc = wv * 8 + i;
      const shortx8 g = *(const shortx8*)(&T[((size_t)k8loc * 64 + (lane ^ k8loc)) * 8]);
      *(shortx8*)(W2 + ((size_t)(kb * 64 + k8loc) * 256 + n0 + lane) * 8) = g;
    }
    __syncthreads();
  }
}

// ---------------------------------------------------------------------------
// build_A v2: x -> A2[k8][bc][8] bf16. Verified R5/R6 structure (contiguous
// half-wave stores, XSTR=513 conflict-free gather); loads BATCHED:
//  - staging: all 16 float2 into regs, then ds_write (was load->write pairs)
//  - gather tables: task-0 e_idx/signs loaded pre-barrier; next task's tables
//    reloaded right after the gather consumes them (stores hide the latency)
// ---------------------------------------------------------------------------
__global__ __launch_bounds__(512, 4) void build_A(
    const float* __restrict__ x, const int* __restrict__ rxd_perm,
    const int* __restrict__ e_idx, const float* __restrict__ signs,
    unsigned short* __restrict__ A2) {
  __shared__ __align__(16) float xr[32 * XSTR];   // 65664 B
  const int t    = threadIdx.x;
  const int lane = t & 63;
  const int wv   = t >> 6;

  const int blk = blockIdx.x;           // 0..511
  const int r   = blk >> 3;
  const int bcg = blk & 7;
  const int pr  = rxd_perm[r];

  const int row0 = wv * 4 + (lane >> 5);          // i=0 row
  const int row1 = row0 + 2;                      // i=1 row
  const int ec   = (lane & 31) * 2;

  // batch staging loads (16 independent dwordx2 in flight)
  float2 rv0[8], rv1[8];
  {
    const float* xs0 = x + ((size_t)(bcg * 32 + row0) * R_ + pr) * E_;
    const float* xs1 = x + ((size_t)(bcg * 32 + row1) * R_ + pr) * E_;
    #pragma unroll
    for (int p = 0; p < 8; ++p) rv0[p] = *(const float2*)(xs0 + p * 64 + ec);
    #pragma unroll
    for (int p = 0; p < 8; ++p) rv1[p] = *(const float2*)(xs1 + p * 64 + ec);
  }
  // write LDS: banks (row+e)%32, parities interleave -> 2/bank (free)
  {
    float* xd0 = xr + (size_t)row0 * XSTR;
    float* xd1 = xr + (size_t)row1 * XSTR;
    #pragma unroll
    for (int p = 0; p < 8; ++p) {
      xd0[p * 64 + ec] = rv0[p].x; xd0[p * 64 + ec + 1] = rv0[p].y;
    }
    #pragma unroll
    for (int p = 0; p < 8; ++p) {
      xd1[p * 64 + ec] = rv1[p].x; xd1[p * 64 + ec + 1] = rv1[p].y;
    }
  }

  // task-0 gather tables, issued before the barrier (independent of LDS)
  uint4  ei[8];
  float4 sg[8];
  {
    const int e00 = (t >> 5) * 8;                 // task 0: l = t>>5
    #pragma unroll
    for (int i = 0; i < 8; ++i) {
      ei[i] = *(const uint4*)(e_idx + (size_t)(e00 + i) * 4);
      sg[i] = *(const float4*)(signs + (size_t)(e00 + i) * 4);
    }
  }
  __syncthreads();

  const int bcl = t & 31;
  const int bc  = bcg * 32 + bcl;
  const float* xp = xr + (size_t)bcl * XSTR;

  #pragma unroll 1
  for (int task = 0; task < 4; ++task) {
    const int l = task * 16 + (t >> 5);           // e-granule (same per half-wave)

    float v[4][8];
    #pragma unroll
    for (int i = 0; i < 8; ++i) {
      v[0][i] = xp[ei[i].x] * sg[i].x;
      v[1][i] = xp[ei[i].y] * sg[i].y;
      v[2][i] = xp[ei[i].z] * sg[i].z;
      v[3][i] = xp[ei[i].w] * sg[i].w;
    }
    // reload tables for next task; pools+stores below hide the latency
    if (task < 3) {
      const int e0n = ((task + 1) * 16 + (t >> 5)) * 8;
      #pragma unroll
      for (int i = 0; i < 8; ++i) {
        ei[i] = *(const uint4*)(e_idx + (size_t)(e0n + i) * 4);
        sg[i] = *(const float4*)(signs + (size_t)(e0n + i) * 4);
      }
    }

    // k8 = p*4096 + r*64 + l; store granule (k8, bc).
    // Per half-wave: 32 lanes x 16 B = 512 B contiguous.
    unsigned short* dst = A2 + ((size_t)(r * 64 + l) * 256 + bc) * 8;
    shortx8 o;

    // p=0: passthrough
    #pragma unroll
    for (int i = 0; i < 8; ++i) o[i] = (short)f2bf(v[0][i]);
    *(shortx8*)(dst) = o;

    // p=1: k=2 windows, first-max wins
    #pragma unroll
    for (int j = 0; j < 4; ++j) {
      const float a = v[1][2 * j], b = v[1][2 * j + 1];
      const bool first = (a >= b);
      o[2 * j]     = (short)f2bf(first ? a : 0.0f);
      o[2 * j + 1] = (short)f2bf(first ? 0.0f : b);
    }
    *(shortx8*)(dst + (size_t)4096 * 256 * 8) = o;

    // p=2: k=4 windows
    #pragma unroll
    for (int j = 0; j < 2; ++j) {
      int am = 0; float m = v[2][4 * j];
      #pragma unroll
      for (int i = 1; i < 4; ++i)
        if (v[2][4 * j + i] > m) { m = v[2][4 * j + i]; am = i; }
      #pragma unroll
      for (int i = 0; i < 4; ++i) o[4 * j + i] = (short)f2bf(i == am ? m : 0.0f);
    }
    *(shortx8*)(dst + (size_t)2 * 4096 * 256 * 8) = o;

    // p=3: k=8 window
    {
      int am = 0; float m = v[3][0];
      #pragma unroll
      for (int i = 1; i < 8; ++i)
        if (v[3][i] > m) { m = v[3][i]; am = i; }
      #pragma unroll
      for (int i = 0; i < 8; ++i) o[i] = (short)f2bf(i == am ? m : 0.0f);
    }
    *(shortx8*)(dst + (size_t)3 * 4096 * 256 * 8) = o;
  }
}

// ---------------------------------------------------------------------------
// Split-K GEMM on k-slab layout (UNCHANGED — measured ~39 µs, near its
// traffic floor): per iter GLDS 16 KB (A2) + 8 KB (W2), fully contiguous;
// fragments read directly as 16-B granules. Double-buffered, 48 KB LDS.
// ---------------------------------------------------------------------------
__global__ __launch_bounds__(512, 4) void gemm_splitk(
    const unsigned short* __restrict__ A2, const unsigned short* __restrict__ W2,
    float* __restrict__ Pp) {
  __shared__ unsigned short As[2][4 * 256 * 8];   // 2 x 16 KB
  __shared__ unsigned short Ws[2][4 * 128 * 8];   // 2 x 8 KB
  const int t    = threadIdx.x;
  const int lane = t & 63;
  const int wv   = t >> 6;                  // 0..7

  const int id = blockIdx.x;                // 0..511
  const int ny = (id >> 3) & 1;
  const int z  = (id & 7) | ((id >> 4) << 3);
  const int nBase = ny * BN;

  const int wm   = (wv >> 1) * 64;
  const int wn   = (wv & 1) * 64;
  const int lrow = lane & 15;
  const int quad = lane >> 4;

  floatx4 acc[4][4];
  #pragma unroll
  for (int i = 0; i < 4; ++i)
    #pragma unroll
    for (int j = 0; j < 4; ++j) acc[i][j] = {0.f, 0.f, 0.f, 0.f};

  auto stage = [&](int buf, int it) {
    const size_t g0 = (size_t)(z * 64 + it * 4) * 256;   // 4 slabs x 256 granules
    #pragma unroll
    for (int c = 0; c < 2; ++c) {
      const int slot = (wv * 2 + c) * 64 + lane;         // 0..1023
      GLDS16(A2 + (g0 + slot) * 8, &As[buf][slot * 8]);
    }
    const int wslot = wv * 64 + lane;                    // 0..511
    const int slab  = wslot >> 7;                        // uniform per wave
    const int nloc  = wslot & 127;
    GLDS16(W2 + (g0 + (size_t)slab * 256 + nBase + nloc) * 8, &Ws[buf][wslot * 8]);
  };
  auto compute = [&](int buf) {
    shortx8 af[4], wf[4];
    #pragma unroll
    for (int ti = 0; ti < 4; ++ti)
      af[ti] = *(const shortx8*)(&As[buf][(quad * 256 + wm + ti * 16 + lrow) * 8]);
    #pragma unroll
    for (int tj = 0; tj < 4; ++tj)
      wf[tj] = *(const shortx8*)(&Ws[buf][(quad * 128 + wn + tj * 16 + lrow) * 8]);
    #pragma unroll
    for (int ti = 0; ti < 4; ++ti)
      #pragma unroll
      for (int tj = 0; tj < 4; ++tj)
        acc[ti][tj] = __builtin_amdgcn_mfma_f32_16x16x32_bf16(
            af[ti], wf[tj], acc[ti][tj], 0, 0, 0);
  };

  stage(0, 0);
  __syncthreads();

  for (int it = 0; it < ITERS; ++it) {
    const int b = it & 1;
    if (it + 1 < ITERS) stage(b ^ 1, it + 1);  // fire-and-forget prefetch
    compute(b);
    __syncthreads();                            // vmcnt(0): buffer b^1 ready
  }

  float* Pz = Pp + (size_t)z * (M_ * OS_);
  #pragma unroll
  for (int ti = 0; ti < 4; ++ti)
    #pragma unroll
    for (int tj = 0; tj < 4; ++tj)
      #pragma unroll
      for (int j = 0; j < 4; ++j) {
        const int m = wm + ti * 16 + quad * 4 + j;
        const int n = nBase + wn + tj * 16 + lrow;
        Pz[(size_t)m * OS_ + n] = acc[ti][tj][j];
      }
}

// out[m,n] = bias[n] + sum_z P[z,m,n]; 2-way z-split, halves combined via LDS
__global__ __launch_bounds__(256) void reduce_out(
    const float* __restrict__ Pp, const float* __restrict__ bias,
    float* __restrict__ out) {
  __shared__ float4 part[128];
  const int t    = threadIdx.x;                    // 0..255
  const int i4   = blockIdx.x * 128 + (t & 127);   // 0..16383
  const int half = t >> 7;
  const float* p = Pp + (size_t)i4 * 4 + (size_t)half * 128 * (M_ * OS_);
  float4 s = {0.f, 0.f, 0.f, 0.f};
  #pragma unroll 8
  for (int zz = 0; zz < 128; ++zz) {
    const float4 v = *(const float4*)(p + (size_t)zz * (M_ * OS_));
    s.x += v.x; s.y += v.y; s.z += v.z; s.w += v.w;
  }
  if (half) part[t & 127] = s;
  __syncthreads();
  if (!half) {
    const float4 q = part[t];
    const float4 bb = *(const float4*)(bias + ((i4 * 4) & (OS_ - 1)));
    float4 o = {s.x + q.x + bb.x, s.y + q.y + bb.y,
                s.z + q.z + bb.z, s.w + q.w + bb.w};
    *(float4*)(out + (size_t)i4 * 4) = o;
  }
}

extern "C" void kernel_launch(void* const* d_in, const int* in_sizes, int n_in,
                              void* d_out, int out_size, void* d_ws, size_t ws_size,
                              hipStream_t stream) {
  const float* x        = (const float*)d_in[0];
  const int*   rxd_perm = (const int*)d_in[1];
  const int*   e_idx    = (const int*)d_in[2];
  const float* signs    = (const float*)d_in[3];
  const float* W        = (const float*)d_in[4];
  const float* bias     = (const float*)d_in[5];
  float* out = (float*)d_out;

  unsigned short* A2 = (unsigned short*)d_ws;                          // 67.1 MB
  unsigned short* W2 = (unsigned short*)((char*)d_ws + 67108864);      // 67.1 MB
  float*          Pp = (float*)((char*)d_ws + 134217728);              // 67.1 MB

  convW_k<<<dim3(512), dim3(512), 0, stream>>>(W, W2);
  build_A<<<dim3(512), dim3(512), 0, stream>>>(x, rxd_perm, e_idx, signs, A2);
  gemm_splitk<<<dim3(2 * Z_), dim3(512), 0, stream>>>(A2, W2, Pp);
  reduce_out<<<dim3(128), dim3(256), 0, stream>>>(Pp, bias, out);
}

// Round 8
// 275.628 us; speedup vs baseline: 1.1559x; 1.1559x over previous
//
#include <hip/hip_runtime.h>
#include <stdint.h>

#define B_ 64
#define C_ 4
#define R_ 64
#define E_ 512
#define P_ 4
#define OS_ 256
#define L_ 32768          // R_*E_
#define K_ 131072         // L_*P_
#define M_ 256            // B_*C_

#define BM 256
#define BN 64             // W-tile [64 n][512 k] bf16 = 64 KB -> fully LDS-resident
#define Z_ 256            // split-K slices (KCH=512)
#define KCH (K_/Z_)       // 512

#define XSTR 513          // padded x-row stride (f32): bank=(bcl+e)%32

typedef float  floatx4 __attribute__((ext_vector_type(4)));
typedef short  shortx8 __attribute__((ext_vector_type(8)));

static __device__ __forceinline__ unsigned short f2bf(float f) {
  union { float f; unsigned int u; } v; v.f = f;
  unsigned int u = v.u;
  u += 0x7fffu + ((u >> 16) & 1u);   // RNE
  return (unsigned short)(u >> 16);
}

// ---------------------------------------------------------------------------
// build_A (R6-verified version, reverted from R7's regression): x ->
// A2[k8][bc][8] bf16 k-slab granules. Contiguous half-wave stores + XSTR=513
// conflict-free gather (262K conflict cycles measured in R5).
// ---------------------------------------------------------------------------
__global__ __launch_bounds__(512) void build_A(
    const float* __restrict__ x, const int* __restrict__ rxd_perm,
    const int* __restrict__ e_idx, const float* __restrict__ signs,
    unsigned short* __restrict__ A2) {
  __shared__ __align__(16) float xr[32 * XSTR];   // 65664 B
  const int t    = threadIdx.x;
  const int lane = t & 63;
  const int wv   = t >> 6;

  const int blk = blockIdx.x;           // 0..511
  const int r   = blk >> 3;
  const int bcg = blk & 7;
  const int pr  = rxd_perm[r];

  // stage: wave wv owns rows wv*4..wv*4+3; per instr 2 rows x 256 B global,
  // scalar LDS writes at banks (row+e)%32: parities interleave -> 2/bank.
  #pragma unroll
  for (int i = 0; i < 2; ++i) {
    const int row = wv * 4 + i * 2 + (lane >> 5);
    const float* xsrc = x + ((size_t)(bcg * 32 + row) * R_ + pr) * E_;
    float* xd = xr + (size_t)row * XSTR;
    #pragma unroll
    for (int pass = 0; pass < 8; ++pass) {
      const int e = pass * 64 + (lane & 31) * 2;
      const float2 v = *(const float2*)(xsrc + e);
      xd[e]     = v.x;
      xd[e + 1] = v.y;
    }
  }
  __syncthreads();

  const int bcl = t & 31;
  const int bc  = bcg * 32 + bcl;
  const float* xp = xr + (size_t)bcl * XSTR;

  #pragma unroll 1
  for (int task = 0; task < 4; ++task) {
    const int l  = task * 16 + (t >> 5);   // e-granule 0..63 (same per half-wave)
    const int e0 = l * 8;

    float v[4][8];
    #pragma unroll
    for (int i = 0; i < 8; ++i) {
      const uint4  ei = *(const uint4*)(e_idx + (size_t)(e0 + i) * 4);
      const float4 sg = *(const float4*)(signs + (size_t)(e0 + i) * 4);
      v[0][i] = xp[ei.x] * sg.x;
      v[1][i] = xp[ei.y] * sg.y;
      v[2][i] = xp[ei.z] * sg.z;
      v[3][i] = xp[ei.w] * sg.w;
    }

    // k8 = p*4096 + r*64 + l; store granule (k8, bc).
    // Per half-wave: 32 lanes x 16 B = 512 B contiguous.
    unsigned short* dst = A2 + ((size_t)(r * 64 + l) * 256 + bc) * 8;
    shortx8 o;

    // p=0: passthrough
    #pragma unroll
    for (int i = 0; i < 8; ++i) o[i] = (short)f2bf(v[0][i]);
    *(shortx8*)(dst) = o;

    // p=1: k=2 windows, first-max wins
    #pragma unroll
    for (int j = 0; j < 4; ++j) {
      const float a = v[1][2 * j], b = v[1][2 * j + 1];
      const bool first = (a >= b);
      o[2 * j]     = (short)f2bf(first ? a : 0.0f);
      o[2 * j + 1] = (short)f2bf(first ? 0.0f : b);
    }
    *(shortx8*)(dst + (size_t)4096 * 256 * 8) = o;

    // p=2: k=4 windows
    #pragma unroll
    for (int j = 0; j < 2; ++j) {
      int am = 0; float m = v[2][4 * j];
      #pragma unroll
      for (int i = 1; i < 4; ++i)
        if (v[2][4 * j + i] > m) { m = v[2][4 * j + i]; am = i; }
      #pragma unroll
      for (int i = 0; i < 4; ++i) o[4 * j + i] = (short)f2bf(i == am ? m : 0.0f);
    }
    *(shortx8*)(dst + (size_t)2 * 4096 * 256 * 8) = o;

    // p=3: k=8 window
    {
      int am = 0; float m = v[3][0];
      #pragma unroll
      for (int i = 1; i < 8; ++i)
        if (v[3][i] > m) { m = v[3][i]; am = i; }
      #pragma unroll
      for (int i = 0; i < 8; ++i) o[i] = (short)f2bf(i == am ? m : 0.0f);
    }
    *(shortx8*)(dst + (size_t)3 * 4096 * 256 * 8) = o;
  }
}

// ---------------------------------------------------------------------------
// gemm_fw: fused W-conversion + split-K GEMM (convW/W2 DELETED: -201 MB).
// Block (z, ny): stages W[ny*64+n][z*512..+512] f32 ONCE into 64 KB LDS as
// bf16 k-slab granules (convW's verified 2KB-contiguous row reads; XOR (n^k8)
// swizzle = conflict-free write AND read). A-fragments are read DIRECTLY
// global->VGPR (each = one 16-B k-slab granule; 4x256B contiguous per
// wave-instr) — no As LDS, no main-loop barriers. A2 re-read x4 (ny) is
// L3-hot; same-z blocks share an XCD (id=ny*256+z, 256%8==0) for L2 reuse.
// ---------------------------------------------------------------------------
__global__ __launch_bounds__(512, 4) void gemm_fw(
    const unsigned short* __restrict__ A2, const float* __restrict__ W,
    float* __restrict__ Pp) {
  __shared__ unsigned short Ws[64 * 64 * 8];   // 64 KB: granule (k8, n^k8)
  const int t    = threadIdx.x;
  const int lane = t & 63;
  const int wv   = t >> 6;                  // 0..7
  const int id   = blockIdx.x;              // 0..1023
  const int z    = id & 255;
  const int ny   = id >> 8;                 // 0..3
  const int lrow = lane & 15;
  const int quad = lane >> 4;

  // ---- stage W tile: 64 rows x 512 f32; per wave-instr 2 KB contiguous ----
  // lane owns k8=lane (f32 k = lane*8..+7); granule (k8=lane, n=row^lane)
  const float* wb = W + (size_t)(ny * 64) * K_ + (size_t)z * 512 + lane * 8;
  float4 wa[8][2];
  #pragma unroll
  for (int i = 0; i < 8; ++i) {             // 16 independent dwordx4 in flight
    const float* wp = wb + (size_t)(wv * 8 + i) * K_;
    wa[i][0] = *(const float4*)(wp);
    wa[i][1] = *(const float4*)(wp + 4);
  }
  #pragma unroll
  for (int i = 0; i < 8; ++i) {
    shortx8 g;
    g[0] = (short)f2bf(wa[i][0].x); g[1] = (short)f2bf(wa[i][0].y);
    g[2] = (short)f2bf(wa[i][0].z); g[3] = (short)f2bf(wa[i][0].w);
    g[4] = (short)f2bf(wa[i][1].x); g[5] = (short)f2bf(wa[i][1].y);
    g[6] = (short)f2bf(wa[i][1].z); g[7] = (short)f2bf(wa[i][1].w);
    *(shortx8*)(&Ws[((size_t)lane * 64 + ((wv * 8 + i) ^ lane)) * 8]) = g;
  }
  __syncthreads();                          // W resident; no more barriers

  floatx4 acc[2][4];
  #pragma unroll
  for (int i = 0; i < 2; ++i)
    #pragma unroll
    for (int j = 0; j < 4; ++j) acc[i][j] = {0.f, 0.f, 0.f, 0.f};

  // a-frag granule base: (k8 = z*64 + s*4 + quad, m = wv*32 + ti*16 + lrow)
  const unsigned short* ab =
      A2 + ((size_t)(z * 64 + quad) * 256 + wv * 32 + lrow) * 8;

  #pragma unroll
  for (int s = 0; s < 16; ++s) {            // full unroll: scheduler hoists loads
    const shortx8 af0 = *(const shortx8*)(ab + (size_t)s * 8192);
    const shortx8 af1 = *(const shortx8*)(ab + (size_t)s * 8192 + 128);
    const int k8l = s * 4 + quad;
    shortx8 wf[4];
    #pragma unroll
    for (int tj = 0; tj < 4; ++tj)
      wf[tj] = *(const shortx8*)(&Ws[((size_t)k8l * 64 + ((tj * 16 + lrow) ^ k8l)) * 8]);
    #pragma unroll
    for (int tj = 0; tj < 4; ++tj) {
      acc[0][tj] = __builtin_amdgcn_mfma_f32_16x16x32_bf16(af0, wf[tj], acc[0][tj], 0, 0, 0);
      acc[1][tj] = __builtin_amdgcn_mfma_f32_16x16x32_bf16(af1, wf[tj], acc[1][tj], 0, 0, 0);
    }
  }

  // epilogue: plain stores of the split-K partial slice [256 m][64 n]
  float* Pz = Pp + (size_t)z * (M_ * OS_) + ny * 64;
  #pragma unroll
  for (int ti = 0; ti < 2; ++ti)
    #pragma unroll
    for (int tj = 0; tj < 4; ++tj)
      #pragma unroll
      for (int j = 0; j < 4; ++j) {
        const int m = wv * 32 + ti * 16 + quad * 4 + j;
        const int n = tj * 16 + lrow;
        Pz[(size_t)m * OS_ + n] = acc[ti][tj][j];
      }
}

// out[m,n] = bias[n] + sum_z P[z,m,n]; 2-way z-split, halves combined via LDS
__global__ __launch_bounds__(256) void reduce_out(
    const float* __restrict__ Pp, const float* __restrict__ bias,
    float* __restrict__ out) {
  __shared__ float4 part[128];
  const int t    = threadIdx.x;                    // 0..255
  const int i4   = blockIdx.x * 128 + (t & 127);   // 0..16383
  const int half = t >> 7;
  const float* p = Pp + (size_t)i4 * 4 + (size_t)half * 128 * (M_ * OS_);
  float4 s = {0.f, 0.f, 0.f, 0.f};
  #pragma unroll 8
  for (int zz = 0; zz < 128; ++zz) {
    const float4 v = *(const float4*)(p + (size_t)zz * (M_ * OS_));
    s.x += v.x; s.y += v.y; s.z += v.z; s.w += v.w;
  }
  if (half) part[t & 127] = s;
  __syncthreads();
  if (!half) {
    const float4 q = part[t];
    const float4 bb = *(const float4*)(bias + ((i4 * 4) & (OS_ - 1)));
    float4 o = {s.x + q.x + bb.x, s.y + q.y + bb.y,
                s.z + q.z + bb.z, s.w + q.w + bb.w};
    *(float4*)(out + (size_t)i4 * 4) = o;
  }
}

extern "C" void kernel_launch(void* const* d_in, const int* in_sizes, int n_in,
                              void* d_out, int out_size, void* d_ws, size_t ws_size,
                              hipStream_t stream) {
  const float* x        = (const float*)d_in[0];
  const int*   rxd_perm = (const int*)d_in[1];
  const int*   e_idx    = (const int*)d_in[2];
  const float* signs    = (const float*)d_in[3];
  const float* W        = (const float*)d_in[4];
  const float* bias     = (const float*)d_in[5];
  float* out = (float*)d_out;

  unsigned short* A2 = (unsigned short*)d_ws;                    // 67.1 MB
  float*          Pp = (float*)((char*)d_ws + 67108864);         // 67.1 MB

  build_A<<<dim3(512), dim3(512), 0, stream>>>(x, rxd_perm, e_idx, signs, A2);
  gemm_fw<<<dim3(1024), dim3(512), 0, stream>>>(A2, W, Pp);
  reduce_out<<<dim3(128), dim3(256), 0, stream>>>(Pp, bias, out);
}